// Round 2
// baseline (437.930 us; speedup 1.0000x reference)
//
#include <hip/hip_runtime.h>

typedef __attribute__((ext_vector_type(8))) short short8;
typedef __attribute__((ext_vector_type(4))) float f32x4;
typedef unsigned short u16;

// ---------- bf16 helpers ----------
__device__ __forceinline__ u16 f2bf(float x) {
    unsigned u = __builtin_bit_cast(unsigned, x);
    u += 0x7fff + ((u >> 16) & 1);          // round-to-nearest-even
    return (u16)(u >> 16);
}
__device__ __forceinline__ float bf2f(u16 h) {
    return __builtin_bit_cast(float, ((unsigned)h) << 16);
}

// ---------- async global->LDS (16B/lane) ----------
__device__ __forceinline__ void g2l16(const u16* g, u16* lds_wave_base) {
    __builtin_amdgcn_global_load_lds(
        (const __attribute__((address_space(1))) void*)g,
        (__attribute__((address_space(3))) void*)lds_wave_base,
        16, 0, 0);
}

// ---------- epilogue store dispatch ----------
__device__ __forceinline__ void storeC(float* C, size_t i, float v) { C[i] = v; }
__device__ __forceinline__ void storeC(u16* C, size_t i, float v)   { C[i] = f2bf(v); }

// ---------- mask dtype detection ----------
// If mask is uint8 bool: bytes at offsets %4 != 0 within the first 4KB are random
// bools -> some nonzero (certain for random data). If int32 {0,1}: those bytes are
// all zero. flag = 1 -> uint8, flag = 0 -> int32.
__global__ void detect_mask_kernel(const unsigned char* __restrict__ m, int* __restrict__ flag) {
    __shared__ int any;
    if (threadIdx.x == 0) any = 0;
    __syncthreads();
    int base = threadIdx.x * 16;
    int local = 0;
#pragma unroll
    for (int j = 0; j < 16; ++j) {
        int idx = base + j;
        if ((idx & 3) != 0 && m[idx] != 0) local = 1;
    }
    if (local) atomicOr(&any, 1);
    __syncthreads();
    if (threadIdx.x == 0) flag[0] = any;
}

// ---------- cast fp32 -> bf16 hi (+ optional lo, + optional copy into cat right half) ----------
__global__ __launch_bounds__(256) void cast_split_kernel(
    const float* __restrict__ x, u16* __restrict__ hi, u16* __restrict__ lo,
    u16* __restrict__ cat_right /* already offset by +1024, row stride 2048 */, long n)
{
    long i = ((long)blockIdx.x * 256 + threadIdx.x) * 4;
    if (i >= n) return;
    const float4 v = *(const float4*)(x + i);
    float f[4] = {v.x, v.y, v.z, v.w};
    u16 h[4], l[4];
#pragma unroll
    for (int j = 0; j < 4; ++j) {
        h[j] = f2bf(f[j]);
        l[j] = f2bf(f[j] - bf2f(h[j]));   // exact residual, then RNE
    }
    ushort4 hv = make_ushort4(h[0], h[1], h[2], h[3]);
    *(ushort4*)(hi + i) = hv;
    if (lo) *(ushort4*)(lo + i) = make_ushort4(l[0], l[1], l[2], l[3]);
    if (cat_right) {
        long row = i >> 10, col = i & 1023;     // D = 1024
        *(ushort4*)(cat_right + row * 2048 + col) = hv;
    }
}

// ---------- bf16 transpose: enc_hi [b][2048 k][1024 d] -> encT [b][1024 d][2048 k] ----------
__global__ __launch_bounds__(256) void transpose_kernel(const u16* __restrict__ src,
                                                        u16* __restrict__ dst)
{
    __shared__ u16 tile[32][33];
    const int b  = blockIdx.z;
    const int k0 = blockIdx.x * 32;
    const int d0 = blockIdx.y * 32;
    const int tx = threadIdx.x, ty = threadIdx.y;   // block (32, 8)
    const u16* s = src + ((size_t)b * 2048 + k0) * 1024 + d0;
#pragma unroll
    for (int i = 0; i < 4; ++i)
        tile[ty + i * 8][tx] = s[(size_t)(ty + i * 8) * 1024 + tx];
    __syncthreads();
    u16* d = dst + ((size_t)b * 1024 + d0) * 2048 + k0;
#pragma unroll
    for (int i = 0; i < 4; ++i)
        d[(size_t)(ty + i * 8) * 2048 + tx] = tile[tx][ty + i * 8];
}

// ---------- GEMM: C[M][N] = A[M][K] * B[N][K]^T   (both operands k-contiguous) ----------
// 128x128 tile, BK=32, 256 threads = 4 waves in 2x2, each wave 64x64 (4x4 frags of 16x16x32).
// SPLIT==3: A = Ah+Al, B = Bh+Bl, acc = Ah*Bh + Ah*Bl + Al*Bh  (near-fp32 product)
template<int SPLIT, bool MASKED, typename CT>
__global__ __launch_bounds__(256) void gemm_bt_kernel(
    const u16* __restrict__ Ah, const u16* __restrict__ Al, int lda, long sAb,
    const u16* __restrict__ Bh, const u16* __restrict__ Bl, int ldb, long sBb,
    CT* __restrict__ C, int ldc, long sCb,
    const void* __restrict__ mask, const int* __restrict__ mflagp, long sMb,
    int K)
{
    extern __shared__ u16 smem[];
    u16* sAh = smem;            // 128*32
    u16* sBh = smem + 4096;
    u16* sAl = smem + 8192;     // only used when SPLIT==3
    u16* sBl = smem + 12288;

    const int t    = threadIdx.x;
    const int bz   = blockIdx.z;
    const int row0 = blockIdx.y * 128;   // within-batch row
    const int col0 = blockIdx.x * 128;

    Ah += (size_t)bz * sAb;
    Bh += (size_t)bz * sBb;
    C  += (size_t)bz * sCb;
    if constexpr (SPLIT == 3) { Al += (size_t)bz * sAb; Bl += (size_t)bz * sBb; }

    const int lane = t & 63, wid = t >> 6;
    const int wr = wid >> 1, wc = wid & 1;
    const int lr = lane & 15, lk = lane >> 4;

    const int rs = t >> 2;            // staging row 0..63
    const int cs = (t & 3) * 8;       // staging col chunk
    const int wb = (t >> 6) * 512;    // wave-uniform LDS base (elements)

    f32x4 acc[4][4] = {};

    for (int k0 = 0; k0 < K; k0 += 32) {
        const size_t aoff = (size_t)(row0 + rs) * lda + k0 + cs;
        const size_t boff = (size_t)(col0 + rs) * ldb + k0 + cs;
        g2l16(Ah + aoff,                     sAh + wb);
        g2l16(Ah + aoff + (size_t)64 * lda,  sAh + 2048 + wb);
        g2l16(Bh + boff,                     sBh + wb);
        g2l16(Bh + boff + (size_t)64 * ldb,  sBh + 2048 + wb);
        if constexpr (SPLIT == 3) {
            g2l16(Al + aoff,                     sAl + wb);
            g2l16(Al + aoff + (size_t)64 * lda,  sAl + 2048 + wb);
            g2l16(Bl + boff,                     sBl + wb);
            g2l16(Bl + boff + (size_t)64 * ldb,  sBl + 2048 + wb);
        }
        __syncthreads();

        short8 ah[4], bh[4], al[4], bl[4];
#pragma unroll
        for (int i = 0; i < 4; ++i) {
            ah[i] = *(const short8*)&sAh[(wr * 64 + i * 16 + lr) * 32 + lk * 8];
            bh[i] = *(const short8*)&sBh[(wc * 64 + i * 16 + lr) * 32 + lk * 8];
        }
        if constexpr (SPLIT == 3) {
#pragma unroll
            for (int i = 0; i < 4; ++i) {
                al[i] = *(const short8*)&sAl[(wr * 64 + i * 16 + lr) * 32 + lk * 8];
                bl[i] = *(const short8*)&sBl[(wc * 64 + i * 16 + lr) * 32 + lk * 8];
            }
        }
#pragma unroll
        for (int i = 0; i < 4; ++i)
#pragma unroll
            for (int j = 0; j < 4; ++j) {
                acc[i][j] = __builtin_amdgcn_mfma_f32_16x16x32_bf16(ah[i], bh[j], acc[i][j], 0, 0, 0);
                if constexpr (SPLIT == 3) {
                    acc[i][j] = __builtin_amdgcn_mfma_f32_16x16x32_bf16(ah[i], bl[j], acc[i][j], 0, 0, 0);
                    acc[i][j] = __builtin_amdgcn_mfma_f32_16x16x32_bf16(al[i], bh[j], acc[i][j], 0, 0, 0);
                }
            }
        __syncthreads();
    }

    int mf = 0;
    if constexpr (MASKED) mf = *mflagp;   // 1 -> uint8 bool, 0 -> int32

    // epilogue: D mapping col = lane&15, row = (lane>>4)*4 + reg  [m89/m91-verified]
#pragma unroll
    for (int i = 0; i < 4; ++i) {
        const int rb = row0 + wr * 64 + i * 16 + lk * 4;
#pragma unroll
        for (int j = 0; j < 4; ++j) {
            const int c = col0 + wc * 64 + j * 16 + lr;
#pragma unroll
            for (int r = 0; r < 4; ++r) {
                float v = acc[i][j][r];
                const size_t row = (size_t)(rb + r);
                if constexpr (MASKED) {
                    const size_t midx = (size_t)bz * sMb + row * (size_t)ldc + c;
                    const bool on = mf ? (((const unsigned char*)mask)[midx] != 0)
                                       : (((const int*)mask)[midx] != 0);
                    if (on) v = -__builtin_inff();
                }
                storeC(C, row * (size_t)ldc + c, v);
            }
        }
    }
}

// ---------- row softmax: scores fp32 [8192][2048] -> P bf16 [8192][2048] ----------
__global__ __launch_bounds__(256) void softmax_kernel(const float* __restrict__ S,
                                                      u16* __restrict__ P)
{
    const long row = blockIdx.x;
    const int t = threadIdx.x;
    const int lane = t & 63, wid = t >> 6;
    const float* src = S + row * 2048;
    float4 a = *(const float4*)(src + t * 8);
    float4 b = *(const float4*)(src + t * 8 + 4);
    float v[8] = {a.x, a.y, a.z, a.w, b.x, b.y, b.z, b.w};

    float m = v[0];
#pragma unroll
    for (int i = 1; i < 8; ++i) m = fmaxf(m, v[i]);
#pragma unroll
    for (int off = 32; off; off >>= 1) m = fmaxf(m, __shfl_xor(m, off));
    __shared__ float redm[4];
    __shared__ float reds[4];
    if (lane == 0) redm[wid] = m;
    __syncthreads();
    m = fmaxf(fmaxf(redm[0], redm[1]), fmaxf(redm[2], redm[3]));

    float e[8], s = 0.f;
#pragma unroll
    for (int i = 0; i < 8; ++i) { e[i] = __expf(v[i] - m); s += e[i]; }
#pragma unroll
    for (int off = 32; off; off >>= 1) s += __shfl_xor(s, off);
    if (lane == 0) reds[wid] = s;
    __syncthreads();
    s = (reds[0] + reds[1]) + (reds[2] + reds[3]);
    const float inv = 1.0f / s;

    short8 o;
#pragma unroll
    for (int i = 0; i < 8; ++i) o[i] = (short)f2bf(e[i] * inv);
    *(short8*)(P + row * 2048 + t * 8) = o;
}

// ---------- launch ----------
extern "C" void kernel_launch(void* const* d_in, const int* in_sizes, int n_in,
                              void* d_out, int out_size, void* d_ws, size_t ws_size,
                              hipStream_t stream)
{
    const float* dec  = (const float*)d_in[0];          // [16][512][1024]
    const float* enc  = (const float*)d_in[1];          // [16][2048][1024]
    const void*  mask = (const void*)d_in[2];           // [16][512][2048] bool or int32
    const float* W    = (const float*)d_in[3];          // [1024][2048]
    float* out        = (float*)d_out;                  // [16][512][1024]

    // workspace carve (total 373,293,056 B)
    char* ws = (char*)d_ws;
    u16*   dec_hi = (u16*)ws;                 ws += 16777216;   // 8192x1024 bf16
    u16*   dec_lo = (u16*)ws;                 ws += 16777216;
    u16*   enc_hi = (u16*)ws;                 ws += 67108864;   // 16x2048x1024 bf16
    u16*   enc_lo = (u16*)ws;                 ws += 67108864;
    u16*   encT   = (u16*)ws;                 ws += 67108864;   // 16x1024x2048 bf16
    u16*   W16    = (u16*)ws;                 ws += 4194304;    // 1024x2048 bf16
    float* scores = (float*)ws;               ws += 67108864;   // 8192x2048 fp32
    u16*   P      = (u16*)ws;                 ws += 33554432;   // 8192x2048 bf16
    u16*   cat    = (u16*)ws;                 ws += 33554432;   // 8192x2048 bf16
    if (ws_size < (size_t)373293056) return;  // scratch too small -> visible failure

    // mask-dtype flag lives in P's first 4 bytes: written at step 0, read at step 3
    // (GEMM1 epilogue), and P itself is only written at step 4 (softmax). No conflict.
    int* mflag = (int*)P;

    // 0) detect mask dtype (uint8 bool vs int32)
    detect_mask_kernel<<<1, 256, 0, stream>>>((const unsigned char*)mask, mflag);

    // 1) casts
    cast_split_kernel<<<8192,  256, 0, stream>>>(dec, dec_hi, dec_lo, cat + 1024, 8388608L);
    cast_split_kernel<<<32768, 256, 0, stream>>>(enc, enc_hi, enc_lo, nullptr,    33554432L);
    cast_split_kernel<<<2048,  256, 0, stream>>>(W,   W16,    nullptr, nullptr,   2097152L);

    // 2) enc_hi -> encT  (per-batch [k][d] -> [d][k])
    transpose_kernel<<<dim3(64, 32, 16), dim3(32, 8), 0, stream>>>(enc_hi, encT);

    // 3) scores = dec @ enc^T (split-bf16, near-fp32) + mask -> fp32
    gemm_bt_kernel<3, true, float><<<dim3(16, 4, 16), 256, 32768, stream>>>(
        dec_hi, dec_lo, 1024, 512L * 1024,
        enc_hi, enc_lo, 1024, 2048L * 1024,
        scores, 2048, 512L * 2048,
        mask, mflag, 512L * 2048, 1024);

    // 4) softmax rows -> P (bf16)
    softmax_kernel<<<8192, 256, 0, stream>>>(scores, P);

    // 5) context = P @ enc  (B = encT), write bf16 into cat[:, 0:1024]
    gemm_bt_kernel<1, false, u16><<<dim3(8, 4, 16), 256, 16384, stream>>>(
        P, nullptr, 2048, 512L * 2048,
        encT, nullptr, 2048, 1024L * 2048,
        cat, 2048, 512L * 2048,
        nullptr, nullptr, 0, 2048);

    // 6) out = cat @ W^T  -> fp32
    gemm_bt_kernel<1, false, float><<<dim3(8, 4, 16), 256, 16384, stream>>>(
        cat, nullptr, 2048, 512L * 2048,
        W16, nullptr, 2048, 0,
        out, 1024, 512L * 1024,
        nullptr, nullptr, 0, 2048);
}

// Round 3
// 367.866 us; speedup vs baseline: 1.1905x; 1.1905x over previous
//
#include <hip/hip_runtime.h>

typedef __attribute__((ext_vector_type(8))) short short8;
typedef __attribute__((ext_vector_type(8))) _Float16 half8;
typedef __attribute__((ext_vector_type(4))) float f32x4;
typedef unsigned short u16;

// ---------- fp16 helpers ----------
__device__ __forceinline__ u16 f2h(float x) {
    return __builtin_bit_cast(u16, (_Float16)x);   // RNE
}

// ---------- async global->LDS (16B/lane) ----------
__device__ __forceinline__ void g2l16(const u16* g, u16* lds_wave_base) {
    __builtin_amdgcn_global_load_lds(
        (const __attribute__((address_space(1))) void*)g,
        (__attribute__((address_space(3))) void*)lds_wave_base,
        16, 0, 0);
}

// ---------- epilogue store dispatch ----------
__device__ __forceinline__ void storeC(float* C, size_t i, float v) { C[i] = v; }
__device__ __forceinline__ void storeC(u16* C, size_t i, float v)   { C[i] = f2h(v); }

// ---------- mask dtype detection ----------
// uint8 bool: bytes at offsets %4!=0 in the first 4KB are random bools -> some nonzero.
// int32 {0,1}: those bytes are all zero. flag=1 -> uint8, flag=0 -> int32.
__global__ void detect_mask_kernel(const unsigned char* __restrict__ m, int* __restrict__ flag) {
    __shared__ int any;
    if (threadIdx.x == 0) any = 0;
    __syncthreads();
    int base = threadIdx.x * 16;
    int local = 0;
#pragma unroll
    for (int j = 0; j < 16; ++j) {
        int idx = base + j;
        if ((idx & 3) != 0 && m[idx] != 0) local = 1;
    }
    if (local) atomicOr(&any, 1);
    __syncthreads();
    if (threadIdx.x == 0) flag[0] = any;
}

// ---------- cast fp32 -> f16 (+ optional copy into cat right half) ----------
__global__ __launch_bounds__(256) void cast_f16_kernel(
    const float* __restrict__ x, u16* __restrict__ dst,
    u16* __restrict__ cat_right /* already offset by +1024, row stride 2048 */, long n)
{
    long i = ((long)blockIdx.x * 256 + threadIdx.x) * 4;
    if (i >= n) return;
    const float4 v = *(const float4*)(x + i);
    ushort4 h = make_ushort4(f2h(v.x), f2h(v.y), f2h(v.z), f2h(v.w));
    *(ushort4*)(dst + i) = h;
    if (cat_right) {
        long row = i >> 10, col = i & 1023;     // D = 1024
        *(ushort4*)(cat_right + row * 2048 + col) = h;
    }
}

// ---------- fused enc cast+transpose: fp32 [b][2048 k][1024 d] -> f16 [k][d] AND f16 [d][k] ----------
__global__ __launch_bounds__(256) void cast_enc_kernel(
    const float* __restrict__ src, u16* __restrict__ enc16, u16* __restrict__ encT)
{
    __shared__ u16 tile[64][68];
    const int b  = blockIdx.z;
    const int k0 = blockIdx.x * 64;
    const int d0 = blockIdx.y * 64;
    const int t  = threadIdx.x;
    const int kr = t >> 4;            // 0..15
    const int dc = (t & 15) * 4;      // 0..60
#pragma unroll
    for (int i = 0; i < 4; ++i) {
        const int k = kr + i * 16;
        const size_t off = ((size_t)(b * 2048 + k0 + k)) * 1024 + d0 + dc;
        const float4 v = *(const float4*)(src + off);
        const u16 h0 = f2h(v.x), h1 = f2h(v.y), h2 = f2h(v.z), h3 = f2h(v.w);
        *(ushort4*)(enc16 + off) = make_ushort4(h0, h1, h2, h3);
        tile[k][dc] = h0; tile[k][dc + 1] = h1; tile[k][dc + 2] = h2; tile[k][dc + 3] = h3;
    }
    __syncthreads();
#pragma unroll
    for (int i = 0; i < 4; ++i) {
        const int d = kr + i * 16;    // reuse decomposition: dr=kr, kc=dc
        ushort4 o = make_ushort4(tile[dc][d], tile[dc + 1][d], tile[dc + 2][d], tile[dc + 3][d]);
        *(ushort4*)(encT + ((size_t)(b * 1024 + d0 + d)) * 2048 + k0 + dc) = o;
    }
}

// ---------- GEMM: C[M][N] = A[M][K] * B[N][K]^T   (both operands k-contiguous, f16) ----------
// 128x128 tile, BK=32, 256 threads = 4 waves in 2x2, each wave 64x64 (4x4 frags of 16x16x32).
template<bool MASKED, typename CT>
__global__ __launch_bounds__(256) void gemm_bt_kernel(
    const u16* __restrict__ A, int lda, long sAb,
    const u16* __restrict__ B, int ldb, long sBb,
    CT* __restrict__ C, int ldc, long sCb,
    const void* __restrict__ mask, const int* __restrict__ mflagp, long sMb,
    int K)
{
    __shared__ u16 smem[8192];
    u16* sA = smem;            // 128*32
    u16* sB = smem + 4096;

    const int t    = threadIdx.x;
    const int bz   = blockIdx.z;
    const int row0 = blockIdx.y * 128;   // within-batch row
    const int col0 = blockIdx.x * 128;

    A += (size_t)bz * sAb;
    B += (size_t)bz * sBb;
    C += (size_t)bz * sCb;

    const int lane = t & 63, wid = t >> 6;
    const int wr = wid >> 1, wc = wid & 1;
    const int lr = lane & 15, lk = lane >> 4;

    const int rs = t >> 2;            // staging row 0..63
    const int cs = (t & 3) * 8;       // staging col chunk
    const int wb = (t >> 6) * 512;    // wave-uniform LDS base (elements)

    f32x4 acc[4][4] = {};

    for (int k0 = 0; k0 < K; k0 += 32) {
        const size_t aoff = (size_t)(row0 + rs) * lda + k0 + cs;
        const size_t boff = (size_t)(col0 + rs) * ldb + k0 + cs;
        g2l16(A + aoff,                     sA + wb);
        g2l16(A + aoff + (size_t)64 * lda,  sA + 2048 + wb);
        g2l16(B + boff,                     sB + wb);
        g2l16(B + boff + (size_t)64 * ldb,  sB + 2048 + wb);
        __syncthreads();

        half8 a[4], b[4];
#pragma unroll
        for (int i = 0; i < 4; ++i) {
            a[i] = *(const half8*)&sA[(wr * 64 + i * 16 + lr) * 32 + lk * 8];
            b[i] = *(const half8*)&sB[(wc * 64 + i * 16 + lr) * 32 + lk * 8];
        }
#pragma unroll
        for (int i = 0; i < 4; ++i)
#pragma unroll
            for (int j = 0; j < 4; ++j)
                acc[i][j] = __builtin_amdgcn_mfma_f32_16x16x32_f16(a[i], b[j], acc[i][j], 0, 0, 0);
        __syncthreads();
    }

    int mf = 0;
    if constexpr (MASKED) mf = *mflagp;   // 1 -> uint8 bool, 0 -> int32

    // epilogue: D mapping col = lane&15, row = (lane>>4)*4 + reg  [m89/m91-verified]
#pragma unroll
    for (int i = 0; i < 4; ++i) {
        const int rb = row0 + wr * 64 + i * 16 + lk * 4;
#pragma unroll
        for (int j = 0; j < 4; ++j) {
            const int c = col0 + wc * 64 + j * 16 + lr;
#pragma unroll
            for (int r = 0; r < 4; ++r) {
                float v = acc[i][j][r];
                const size_t row = (size_t)(rb + r);
                if constexpr (MASKED) {
                    const size_t midx = (size_t)bz * sMb + row * (size_t)ldc + c;
                    const bool on = mf ? (((const unsigned char*)mask)[midx] != 0)
                                       : (((const int*)mask)[midx] != 0);
                    if (on) v = -__builtin_inff();
                }
                storeC(C, row * (size_t)ldc + c, v);
            }
        }
    }
}

// ---------- row softmax: scores fp32 [8192][2048] -> P f16 [8192][2048] ----------
__global__ __launch_bounds__(256) void softmax_kernel(const float* __restrict__ S,
                                                      u16* __restrict__ P)
{
    const long row = blockIdx.x;
    const int t = threadIdx.x;
    const int lane = t & 63, wid = t >> 6;
    const float* src = S + row * 2048;
    float4 a = *(const float4*)(src + t * 8);
    float4 b = *(const float4*)(src + t * 8 + 4);
    float v[8] = {a.x, a.y, a.z, a.w, b.x, b.y, b.z, b.w};

    float m = v[0];
#pragma unroll
    for (int i = 1; i < 8; ++i) m = fmaxf(m, v[i]);
#pragma unroll
    for (int off = 32; off; off >>= 1) m = fmaxf(m, __shfl_xor(m, off));
    __shared__ float redm[4];
    __shared__ float reds[4];
    if (lane == 0) redm[wid] = m;
    __syncthreads();
    m = fmaxf(fmaxf(redm[0], redm[1]), fmaxf(redm[2], redm[3]));

    float e[8], s = 0.f;
#pragma unroll
    for (int i = 0; i < 8; ++i) { e[i] = __expf(v[i] - m); s += e[i]; }
#pragma unroll
    for (int off = 32; off; off >>= 1) s += __shfl_xor(s, off);
    if (lane == 0) reds[wid] = s;
    __syncthreads();
    s = (reds[0] + reds[1]) + (reds[2] + reds[3]);
    const float inv = 1.0f / s;

    short8 o;
#pragma unroll
    for (int i = 0; i < 8; ++i) o[i] = (short)f2h(e[i] * inv);
    *(short8*)(P + row * 2048 + t * 8) = o;
}

// ---------- launch ----------
extern "C" void kernel_launch(void* const* d_in, const int* in_sizes, int n_in,
                              void* d_out, int out_size, void* d_ws, size_t ws_size,
                              hipStream_t stream)
{
    const float* dec  = (const float*)d_in[0];          // [16][512][1024]
    const float* enc  = (const float*)d_in[1];          // [16][2048][1024]
    const void*  mask = (const void*)d_in[2];           // [16][512][2048] bool or int32
    const float* W    = (const float*)d_in[3];          // [1024][2048]
    float* out        = (float*)d_out;                  // [16][512][1024]

    // workspace carve (total 289,406,976 B)
    char* ws = (char*)d_ws;
    u16*   dec16  = (u16*)ws;                 ws += 16777216;   // 8192x1024 f16
    u16*   enc16  = (u16*)ws;                 ws += 67108864;   // 16x2048x1024 f16
    u16*   encT   = (u16*)ws;                 ws += 67108864;   // 16x1024x2048 f16
    u16*   W16    = (u16*)ws;                 ws += 4194304;    // 1024x2048 f16
    float* scores = (float*)ws;               ws += 67108864;   // 8192x2048 fp32
    u16*   P      = (u16*)ws;                 ws += 33554432;   // 8192x2048 f16
    u16*   cat    = (u16*)ws;                 ws += 33554432;   // 8192x2048 f16
    if (ws_size < (size_t)289406976) return;  // scratch too small -> visible failure

    // mask-dtype flag lives in P's first 4 bytes: written at step 0, read at step 3
    // (GEMM1 epilogue), and P itself is only written at step 4 (softmax). No conflict.
    int* mflag = (int*)P;

    // 0) detect mask dtype (uint8 bool vs int32)
    detect_mask_kernel<<<1, 256, 0, stream>>>((const unsigned char*)mask, mflag);

    // 1) casts (dec also fills cat right half; enc fused with transpose)
    cast_f16_kernel<<<8192, 256, 0, stream>>>(dec, dec16, cat + 1024, 8388608L);
    cast_enc_kernel<<<dim3(32, 16, 16), 256, 0, stream>>>(enc, enc16, encT);
    cast_f16_kernel<<<2048, 256, 0, stream>>>(W, W16, nullptr, 2097152L);

    // 2) scores = dec @ enc^T (f16 inputs, fp32 accum) + mask -> fp32
    gemm_bt_kernel<true, float><<<dim3(16, 4, 16), 256, 0, stream>>>(
        dec16, 1024, 512L * 1024,
        enc16, 1024, 2048L * 1024,
        scores, 2048, 512L * 2048,
        mask, mflag, 512L * 2048, 1024);

    // 3) softmax rows -> P (f16)
    softmax_kernel<<<8192, 256, 0, stream>>>(scores, P);

    // 4) context = P @ enc (B = encT), write f16 into cat[:, 0:1024]
    gemm_bt_kernel<false, u16><<<dim3(8, 4, 16), 256, 0, stream>>>(
        P, 2048, 512L * 2048,
        encT, 2048, 1024L * 2048,
        cat, 2048, 512L * 2048,
        nullptr, nullptr, 0, 2048);

    // 5) out = cat @ W^T -> fp32
    gemm_bt_kernel<false, float><<<dim3(8, 4, 16), 256, 0, stream>>>(
        cat, 2048, 512L * 2048,
        W16, 2048, 0,
        out, 1024, 512L * 1024,
        nullptr, nullptr, 0, 2048);
}

// Round 4
// 282.220 us; speedup vs baseline: 1.5517x; 1.3035x over previous
//
#include <hip/hip_runtime.h>

typedef __attribute__((ext_vector_type(8))) _Float16 half8;
typedef __attribute__((ext_vector_type(8))) short short8;
typedef __attribute__((ext_vector_type(4))) float f32x4;
typedef unsigned short u16;

// ---------- fp16 helpers ----------
__device__ __forceinline__ u16 f2h(float x) {
    return __builtin_bit_cast(u16, (_Float16)x);   // RNE
}

// ---------- async global->LDS (16B/lane, linear dest: base + lane*16) ----------
__device__ __forceinline__ void g2l16(const u16* g, u16* l) {
    __builtin_amdgcn_global_load_lds(
        (const __attribute__((address_space(1))) void*)g,
        (__attribute__((address_space(3))) void*)l, 16, 0, 0);
}

// ---------- epilogue store dispatch ----------
__device__ __forceinline__ void storeC(float* C, size_t i, float v) { C[i] = v; }
__device__ __forceinline__ void storeC(u16* C, size_t i, float v)   { C[i] = f2h(v); }

// ---------- mask dtype detection (uint8 bool vs int32) ----------
__global__ void detect_mask_kernel(const unsigned char* __restrict__ m, int* __restrict__ flag) {
    __shared__ int any;
    if (threadIdx.x == 0) any = 0;
    __syncthreads();
    int base = threadIdx.x * 16;
    int local = 0;
#pragma unroll
    for (int j = 0; j < 16; ++j) {
        int idx = base + j;
        if ((idx & 3) != 0 && m[idx] != 0) local = 1;
    }
    if (local) atomicOr(&any, 1);
    __syncthreads();
    if (threadIdx.x == 0) flag[0] = any;
}

// ---------- cast fp32 -> f16 (+ optional copy into cat right half) ----------
__global__ __launch_bounds__(256) void cast_f16_kernel(
    const float* __restrict__ x, u16* __restrict__ dst,
    u16* __restrict__ cat_right, long n)
{
    long i = ((long)blockIdx.x * 256 + threadIdx.x) * 4;
    if (i >= n) return;
    const float4 v = *(const float4*)(x + i);
    ushort4 h = make_ushort4(f2h(v.x), f2h(v.y), f2h(v.z), f2h(v.w));
    *(ushort4*)(dst + i) = h;
    if (cat_right) {
        long row = i >> 10, col = i & 1023;     // D = 1024
        *(ushort4*)(cat_right + row * 2048 + col) = h;
    }
}

// ---------- fused enc cast+transpose: fp32 [b][2048][1024] -> f16 [k][d] AND f16 [d][k] ----------
__global__ __launch_bounds__(256) void cast_enc_kernel(
    const float* __restrict__ src, u16* __restrict__ enc16, u16* __restrict__ encT)
{
    __shared__ u16 tile[64][68];
    const int b  = blockIdx.z;
    const int k0 = blockIdx.x * 64;
    const int d0 = blockIdx.y * 64;
    const int t  = threadIdx.x;
    const int kr = t >> 4;            // 0..15
    const int dc = (t & 15) * 4;      // 0..60
#pragma unroll
    for (int i = 0; i < 4; ++i) {
        const int k = kr + i * 16;
        const size_t off = ((size_t)(b * 2048 + k0 + k)) * 1024 + d0 + dc;
        const float4 v = *(const float4*)(src + off);
        const u16 h0 = f2h(v.x), h1 = f2h(v.y), h2 = f2h(v.z), h3 = f2h(v.w);
        *(ushort4*)(enc16 + off) = make_ushort4(h0, h1, h2, h3);
        tile[k][dc] = h0; tile[k][dc + 1] = h1; tile[k][dc + 2] = h2; tile[k][dc + 3] = h3;
    }
    __syncthreads();
#pragma unroll
    for (int i = 0; i < 4; ++i) {
        const int d = kr + i * 16;
        ushort4 o = make_ushort4(tile[dc][d], tile[dc + 1][d], tile[dc + 2][d], tile[dc + 3][d]);
        *(ushort4*)(encT + ((size_t)(b * 1024 + d0 + d)) * 2048 + k0 + dc) = o;
    }
}

// ---------- 8-wave pipelined GEMM: C[M][N] = A[M][K] * B[N][K]^T (f16, k-contiguous) ----------
// BM=256, BN in {256,128}, BK=64. 8 waves (2 M x 4 N), per-wave output 128 x BN/4.
// T2: XOR chunk swizzle (conflict-free ds_read_b128, pre-swizzled global src).
// T4: counted vmcnt -- next K-tile's 8(6) loads stay in flight across the barrier.
// T5: setprio around MFMA quadrants. 2 barriers per K=64.
template<int BN, bool MASKED, typename CT>
__global__ __launch_bounds__(512, 2) void gemm8_kernel(
    const u16* __restrict__ A, int lda, long sAb,
    const u16* __restrict__ B, int ldb, long sBb,
    CT* __restrict__ C, int ldc, long sCb,
    const void* __restrict__ mask, const int* __restrict__ mflagp, long sMb,
    int K, int nmt, int nnt)
{
    constexpr int BM = 256, BK = 64;
    constexpr int WN  = BN / 4;          // 64 or 32
    constexpr int NF  = WN / 16;         // 4 or 2
    constexpr int NF2 = NF / 2;          // 2 or 1
    constexpr int AE  = BM * BK;         // 16384 elems
    constexpr int BE  = BN * BK;         // 16384 or 8192
    constexpr int ACALLS = 4;            // per-wave staging calls for A
    constexpr int BCALLS = BE / 4096;    // 4 or 2
    constexpr int CALLS  = ACALLS + BCALLS;

    __shared__ u16 smem[2 * (AE + BE)];  // double-buffered A+B K-tiles

    const int t = threadIdx.x;
    const int lane = t & 63, wid = t >> 6;
    const int wr = wid >> 2, wc = wid & 3;
    const int lr = lane & 15, lh = lane >> 4;

    // T1: XCD swizzle (grid 256 = 8 XCD x 32, bijective)
    const int bid = blockIdx.x;
    const int swz = (bid & 7) * ((int)gridDim.x >> 3) + (bid >> 3);
    const int per_b = nmt * nnt;
    const int b   = swz / per_b;
    const int rem = swz % per_b;
    const long row0 = (long)(rem / nnt) * BM;
    const long col0 = (long)(rem % nnt) * BN;

    A += (size_t)b * sAb;
    B += (size_t)b * sBb;
    C += (size_t)b * sCb;

    // staging: chunk ch = wid*64*CALLS_x + c*64 + lane; r = ch>>3, cr = ch&7;
    // source col-chunk = cr ^ (r&7)  (inverse swizzle, involution)
    const int srow = lane >> 3;                       // 0..7
    const int scol = ((lane & 7) ^ (lane >> 3)) * 8;  // element offset in BK
    const u16* pa[ACALLS];
    const u16* pb[BCALLS];
#pragma unroll
    for (int c = 0; c < ACALLS; ++c)
        pa[c] = A + (size_t)(row0 + wid * 8 * ACALLS + c * 8 + srow) * lda + scol;
#pragma unroll
    for (int c = 0; c < BCALLS; ++c)
        pb[c] = B + (size_t)(col0 + wid * 8 * BCALLS + c * 8 + srow) * ldb + scol;

    f32x4 acc[8][NF] = {};

    // swizzled LDS chunk term for ds_read: ((ks*4+lh) ^ (lr&7)) * 8 elems
    const int ch0 = ((0 * 4 + lh) ^ (lr & 7)) * 8;
    const int ch1 = ((1 * 4 + lh) ^ (lr & 7)) * 8;

    const int NT = K / BK;

    // prologue: stage tile 0 into buf 0
    {
        u16* sAn = smem;
        u16* sBn = smem + AE;
#pragma unroll
        for (int c = 0; c < ACALLS; ++c) g2l16(pa[c], sAn + wid * (ACALLS * 512) + c * 512);
#pragma unroll
        for (int c = 0; c < BCALLS; ++c) g2l16(pb[c], sBn + wid * (BCALLS * 512) + c * 512);
    }

    int cur = 0;
    for (int tt = 0; tt < NT; ++tt) {
        if (tt + 1 < NT) {
            // stage next K-tile into the other buffer, THEN wait only for current tile
            const long ko = (long)(tt + 1) * BK;
            u16* sAn = smem + (cur ^ 1) * (AE + BE);
            u16* sBn = sAn + AE;
#pragma unroll
            for (int c = 0; c < ACALLS; ++c) g2l16(pa[c] + ko, sAn + wid * (ACALLS * 512) + c * 512);
#pragma unroll
            for (int c = 0; c < BCALLS; ++c) g2l16(pb[c] + ko, sBn + wid * (BCALLS * 512) + c * 512);
            if constexpr (CALLS == 8) asm volatile("s_waitcnt vmcnt(8)" ::: "memory");
            else                      asm volatile("s_waitcnt vmcnt(6)" ::: "memory");
        } else {
            asm volatile("s_waitcnt vmcnt(0)" ::: "memory");
        }
        __builtin_amdgcn_s_barrier();

        const u16* sAc = smem + cur * (AE + BE);
        const u16* sBc = sAc + AE;

        half8 Ar[4][2], Bq0[NF2][2], Bq1[NF2][2];

        auto ldA = [&](int mh) {
#pragma unroll
            for (int fi = 0; fi < 4; ++fi) {
                const int r = wr * 128 + (mh * 4 + fi) * 16 + lr;
                Ar[fi][0] = *(const half8*)&sAc[r * 64 + ch0];
                Ar[fi][1] = *(const half8*)&sAc[r * 64 + ch1];
            }
        };
        auto ldB = [&](half8 (&Br)[NF2][2], int nh) {
#pragma unroll
            for (int nj = 0; nj < NF2; ++nj) {
                const int r = wc * WN + (nh * NF2 + nj) * 16 + lr;
                Br[nj][0] = *(const half8*)&sBc[r * 64 + ch0];
                Br[nj][1] = *(const half8*)&sBc[r * 64 + ch1];
            }
        };
        auto quad = [&](half8 (&Br)[NF2][2], int mh, int nh) {
            __builtin_amdgcn_s_setprio(1);
#pragma unroll
            for (int fi = 0; fi < 4; ++fi)
#pragma unroll
                for (int nj = 0; nj < NF2; ++nj)
#pragma unroll
                    for (int ks = 0; ks < 2; ++ks)
                        acc[mh * 4 + fi][nh * NF2 + nj] =
                            __builtin_amdgcn_mfma_f32_16x16x32_f16(
                                Ar[fi][ks], Br[nj][ks], acc[mh * 4 + fi][nh * NF2 + nj], 0, 0, 0);
            __builtin_amdgcn_s_setprio(0);
        };

        ldA(0); ldB(Bq0, 0); quad(Bq0, 0, 0);
        ldB(Bq1, 1);         quad(Bq1, 0, 1);
        ldA(1);              quad(Bq1, 1, 1);
                             quad(Bq0, 1, 0);

        __builtin_amdgcn_s_barrier();
        cur ^= 1;
    }

    int mf = 0;
    if constexpr (MASKED) mf = *mflagp;   // 1 -> uint8 bool, 0 -> int32

    // epilogue: C/D mapping col = lane&15, row = (lane>>4)*4 + reg
#pragma unroll
    for (int f = 0; f < 8; ++f) {
        const long rb = row0 + wr * 128 + f * 16 + lh * 4;
#pragma unroll
        for (int n = 0; n < NF; ++n) {
            const long c = col0 + wc * WN + n * 16 + lr;
#pragma unroll
            for (int r = 0; r < 4; ++r) {
                float v = acc[f][n][r];
                const size_t idx = (size_t)(rb + r) * ldc + c;
                if constexpr (MASKED) {
                    const size_t midx = (size_t)b * sMb + idx;
                    const bool on = mf ? (((const unsigned char*)mask)[midx] != 0)
                                       : (((const int*)mask)[midx] != 0);
                    if (on) v = -__builtin_inff();
                }
                storeC(C, idx, v);
            }
        }
    }
}

// ---------- row softmax: scores fp32 [8192][2048] -> P f16 [8192][2048] ----------
__global__ __launch_bounds__(256) void softmax_kernel(const float* __restrict__ S,
                                                      u16* __restrict__ P)
{
    const long row = blockIdx.x;
    const int t = threadIdx.x;
    const int lane = t & 63, wid = t >> 6;
    const float* src = S + row * 2048;
    float4 a = *(const float4*)(src + t * 8);
    float4 b = *(const float4*)(src + t * 8 + 4);
    float v[8] = {a.x, a.y, a.z, a.w, b.x, b.y, b.z, b.w};

    float m = v[0];
#pragma unroll
    for (int i = 1; i < 8; ++i) m = fmaxf(m, v[i]);
#pragma unroll
    for (int off = 32; off; off >>= 1) m = fmaxf(m, __shfl_xor(m, off));
    __shared__ float redm[4];
    __shared__ float reds[4];
    if (lane == 0) redm[wid] = m;
    __syncthreads();
    m = fmaxf(fmaxf(redm[0], redm[1]), fmaxf(redm[2], redm[3]));

    float e[8], s = 0.f;
#pragma unroll
    for (int i = 0; i < 8; ++i) { e[i] = __expf(v[i] - m); s += e[i]; }
#pragma unroll
    for (int off = 32; off; off >>= 1) s += __shfl_xor(s, off);
    if (lane == 0) reds[wid] = s;
    __syncthreads();
    s = (reds[0] + reds[1]) + (reds[2] + reds[3]);
    const float inv = 1.0f / s;

    short8 o;
#pragma unroll
    for (int i = 0; i < 8; ++i) o[i] = (short)f2h(e[i] * inv);
    *(short8*)(P + row * 2048 + t * 8) = o;
}

// ---------- launch ----------
extern "C" void kernel_launch(void* const* d_in, const int* in_sizes, int n_in,
                              void* d_out, int out_size, void* d_ws, size_t ws_size,
                              hipStream_t stream)
{
    const float* dec  = (const float*)d_in[0];          // [16][512][1024]
    const float* enc  = (const float*)d_in[1];          // [16][2048][1024]
    const void*  mask = (const void*)d_in[2];           // [16][512][2048] bool or int32
    const float* W    = (const float*)d_in[3];          // [1024][2048]
    float* out        = (float*)d_out;                  // [16][512][1024]

    // workspace carve (total 289,406,976 B)
    char* ws = (char*)d_ws;
    u16*   dec16  = (u16*)ws;                 ws += 16777216;   // 8192x1024 f16
    u16*   enc16  = (u16*)ws;                 ws += 67108864;   // 16x2048x1024 f16
    u16*   encT   = (u16*)ws;                 ws += 67108864;   // 16x1024x2048 f16
    u16*   W16    = (u16*)ws;                 ws += 4194304;    // 1024x2048 f16
    float* scores = (float*)ws;               ws += 67108864;   // 8192x2048 fp32
    u16*   P      = (u16*)ws;                 ws += 33554432;   // 8192x2048 f16
    u16*   cat    = (u16*)ws;                 ws += 33554432;   // 8192x2048 f16
    if (ws_size < (size_t)289406976) return;

    int* mflag = (int*)P;   // written step 0, read step 2; P body written step 3

    // 0) detect mask dtype
    detect_mask_kernel<<<1, 256, 0, stream>>>((const unsigned char*)mask, mflag);

    // 1) casts
    cast_f16_kernel<<<8192, 256, 0, stream>>>(dec, dec16, cat + 1024, 8388608L);
    cast_enc_kernel<<<dim3(32, 16, 16), 256, 0, stream>>>(enc, enc16, encT);
    cast_f16_kernel<<<2048, 256, 0, stream>>>(W, W16, nullptr, 2097152L);

    // 2) scores = dec @ enc^T + mask  (256x256 tiles, 16b x 2mt x 8nt = 256 blocks)
    gemm8_kernel<256, true, float><<<256, 512, 0, stream>>>(
        dec16, 1024, 512L * 1024,
        enc16, 1024, 2048L * 1024,
        scores, 2048, 512L * 2048,
        mask, mflag, 512L * 2048,
        1024, 2, 8);

    // 3) softmax rows -> P (f16)
    softmax_kernel<<<8192, 256, 0, stream>>>(scores, P);

    // 4) context = P @ encT^T -> cat left half  (256x128 tiles, 16b x 2 x 8 = 256 blocks)
    gemm8_kernel<128, false, u16><<<256, 512, 0, stream>>>(
        P, 2048, 512L * 2048,
        encT, 2048, 1024L * 2048,
        cat, 2048, 512L * 2048,
        nullptr, nullptr, 0,
        2048, 2, 8);

    // 5) out = cat @ W^T -> fp32  (256x128 tiles, 32mt x 8nt = 256 blocks, batch-free)
    gemm8_kernel<128, false, float><<<256, 512, 0, stream>>>(
        cat, 2048, 0,
        W16, 2048, 0,
        out, 1024, 0,
        nullptr, nullptr, 0,
        2048, 32, 8);
}